// Round 2
// baseline (241.354 us; speedup 1.0000x reference)
//
#include <hip/hip_runtime.h>

#define BB 64
#define SS 1024
#define HH 512
#define EE 512
#define VV 32000
#define PP 40

typedef __attribute__((ext_vector_type(8))) __bf16 bf16x8;
typedef __attribute__((ext_vector_type(4))) float f32x4;
typedef __attribute__((ext_vector_type(8))) unsigned short us8_t;
typedef __attribute__((ext_vector_type(4))) unsigned short us4_t;

__device__ inline unsigned short f2bf(float f) {
    unsigned int u = __float_as_uint(f);
    return (unsigned short)((u + 0x7fffu + ((u >> 16) & 1u)) >> 16);
}
__device__ inline float fast_tanh(float x) {
    float e = __expf(-2.0f * fabsf(x));
    float t = (1.0f - e) / (1.0f + e);
    return copysignf(t, x);
}
__device__ inline float sigmf(float x) { return 1.0f / (1.0f + __expf(-x)); }

__device__ inline us8_t pack8(float4 x, float4 y) {
    us8_t u;
    u[0] = f2bf(x.x); u[1] = f2bf(x.y); u[2] = f2bf(x.z); u[3] = f2bf(x.w);
    u[4] = f2bf(y.x); u[5] = f2bf(y.y); u[6] = f2bf(y.z); u[7] = f2bf(y.w);
    return u;
}

// ---------------------------------------------------------------------------
// k_prep: qs = hidden @ W_s^T (blocks 0..63), W_h f32->bf16 (64..95),
//         gate = sigmoid(pos_onehot @ W_p + b_p) (96..351), zero ctx (352..359)
// ---------------------------------------------------------------------------
__global__ __launch_bounds__(256)
void k_prep(const float* __restrict__ hidden, const float* __restrict__ Ws,
            const float* __restrict__ Wh, const float* __restrict__ pos,
            const float* __restrict__ Wp, const float* __restrict__ bp,
            unsigned short* __restrict__ wh16, float* __restrict__ qs,
            float* __restrict__ gate, float* __restrict__ ctx) {
    int blk = blockIdx.x, t = threadIdx.x;
    if (blk < 64) {
        __shared__ float hb[HH];
        int b = blk;
        for (int i = t; i < HH; i += 256) hb[i] = hidden[b * HH + i];
        __syncthreads();
        for (int n = t; n < HH; n += 256) {
            const float* wr = Ws + (size_t)n * HH;
            float acc = 0.0f;
#pragma unroll 4
            for (int k = 0; k < HH; k += 4) {
                float4 w = *(const float4*)(wr + k);
                acc += w.x * hb[k] + w.y * hb[k + 1] + w.z * hb[k + 2] + w.w * hb[k + 3];
            }
            qs[b * HH + n] = acc;
        }
    } else if (blk < 96) {
        int base = (blk - 64) * 8192 + t * 4;
#pragma unroll
        for (int j = 0; j < 8; ++j) {
            int idx = base + j * 1024;
            float4 x = *(const float4*)(Wh + idx);
            us4_t v;
            v[0] = f2bf(x.x); v[1] = f2bf(x.y); v[2] = f2bf(x.z); v[3] = f2bf(x.w);
            *(us4_t*)(wh16 + idx) = v;
        }
    } else if (blk < 352) {
        int idx = (blk - 96) * 256 + t;  // 0..65535 = b*S+s
        const float* pr = pos + (size_t)idx * PP;
        float acc = bp[0];
#pragma unroll
        for (int j = 0; j < 10; ++j) {
            float4 x = *(const float4*)(pr + j * 4);
            acc += x.x * Wp[j * 4] + x.y * Wp[j * 4 + 1] + x.z * Wp[j * 4 + 2] + x.w * Wp[j * 4 + 3];
        }
        gate[idx] = sigmf(acc);
    } else {
        int idx = (blk - 352) * 256 + t;  // 2048 threads x 16 = 32768
#pragma unroll
        for (int j = 0; j < 16; ++j) ctx[idx * 16 + j] = 0.0f;
    }
}

// ---------------------------------------------------------------------------
// k_scores: gated scores[b,s] = gate * V_w . tanh(qs[b] + W_h @ enc[b,s])
// 512 blocks (b x s-chunk-of-128), 8 waves, enc rows in regs (bf16 A-frags),
// W_h bf16 chunks (64 n-rows x 512 K) in LDS with 16B-block XOR swizzle.
// ---------------------------------------------------------------------------
__global__ __launch_bounds__(512)
void k_scores(const float* __restrict__ enc, const unsigned short* __restrict__ wh16,
              const float* __restrict__ qs, const float* __restrict__ Vw,
              const float* __restrict__ gate, const unsigned char* __restrict__ mask,
              float* __restrict__ scores) {
    __shared__ unsigned short whl[64 * 512];  // 64KB
    int b = blockIdx.x >> 3, sc = blockIdx.x & 7;
    int wave = threadIdx.x >> 6, lane = threadIdx.x & 63;
    int l15 = lane & 15, lq = lane >> 4, k0 = lq * 8;
    int s_row = sc * 128 + wave * 16 + l15;
    const float* arow = enc + ((size_t)(b * SS + s_row)) * HH;

    us8_t afr[16];
#pragma unroll
    for (int ks = 0; ks < 16; ++ks) {
        float4 x = *(const float4*)(arow + ks * 32 + k0);
        float4 y = *(const float4*)(arow + ks * 32 + k0 + 4);
        afr[ks] = pack8(x, y);
    }

    float sa0 = 0, sa1 = 0, sa2 = 0, sa3 = 0;
    int str = threadIdx.x >> 3;  // stage row 0..63
    int sseg = threadIdx.x & 7;  // 0..7

    for (int ch = 0; ch < 8; ++ch) {
        __syncthreads();
        {
            const unsigned short* src = wh16 + ((size_t)(ch * 64 + str)) * HH + sseg * 64;
            unsigned short* drow = whl + str * 512;
            int sw = str & 7;
#pragma unroll
            for (int i = 0; i < 8; ++i) {
                int j = sseg * 8 + i;
                us8_t v = *(const us8_t*)(src + i * 8);
                *(us8_t*)(drow + ((j ^ sw) * 8)) = v;
            }
        }
        __syncthreads();
#pragma unroll
        for (int nf = 0; nf < 4; ++nf) {
            int nl = nf * 16 + l15;
            const unsigned short* brow = whl + nl * 512;
            int jx = nl & 7;
            f32x4 acc = {0.0f, 0.0f, 0.0f, 0.0f};
#pragma unroll
            for (int ks = 0; ks < 16; ++ks) {
                int j = ks * 4 + lq;
                us8_t bu = *(const us8_t*)(brow + ((j ^ jx) * 8));
                acc = __builtin_amdgcn_mfma_f32_16x16x32_bf16(
                    __builtin_bit_cast(bf16x8, afr[ks]),
                    __builtin_bit_cast(bf16x8, bu), acc, 0, 0, 0);
            }
            int n = ch * 64 + nf * 16 + l15;
            float qv = qs[b * HH + n];
            float vv = Vw[n];
            sa0 += fast_tanh(acc[0] + qv) * vv;
            sa1 += fast_tanh(acc[1] + qv) * vv;
            sa2 += fast_tanh(acc[2] + qv) * vv;
            sa3 += fast_tanh(acc[3] + qv) * vv;
        }
    }
    // reduce the n dimension (lanes 0..15 of each 16-group)
#pragma unroll
    for (int off = 1; off < 16; off <<= 1) {
        sa0 += __shfl_xor(sa0, off, 64);
        sa1 += __shfl_xor(sa1, off, 64);
        sa2 += __shfl_xor(sa2, off, 64);
        sa3 += __shfl_xor(sa3, off, 64);
    }
    if (l15 == 0) {
        float sv[4] = {sa0, sa1, sa2, sa3};
        int sbase = sc * 128 + wave * 16 + lq * 4;
#pragma unroll
        for (int r = 0; r < 4; ++r) {
            int s = sbase + r;
            float g = gate[b * SS + s];
            float val = mask[b * SS + s] ? -1e30f : sv[r] * g;
            scores[b * SS + s] = val;
        }
    }
}

// ---------------------------------------------------------------------------
// k_softmax: row softmax over S=1024, writes attn to d_out
// ---------------------------------------------------------------------------
__global__ __launch_bounds__(256)
void k_softmax(const float* __restrict__ scores, float* __restrict__ attn) {
    int b = blockIdx.x, t = threadIdx.x;
    int w = t >> 6, ln = t & 63;
    float v0 = scores[b * SS + t];
    float v1 = scores[b * SS + 256 + t];
    float v2 = scores[b * SS + 512 + t];
    float v3 = scores[b * SS + 768 + t];
    float m = fmaxf(fmaxf(v0, v1), fmaxf(v2, v3));
#pragma unroll
    for (int off = 1; off < 64; off <<= 1) m = fmaxf(m, __shfl_xor(m, off, 64));
    __shared__ float sm[4], sl[4];
    if (ln == 0) sm[w] = m;
    __syncthreads();
    m = fmaxf(fmaxf(sm[0], sm[1]), fmaxf(sm[2], sm[3]));
    float e0 = __expf(v0 - m), e1 = __expf(v1 - m), e2 = __expf(v2 - m), e3 = __expf(v3 - m);
    float l = e0 + e1 + e2 + e3;
#pragma unroll
    for (int off = 1; off < 64; off <<= 1) l += __shfl_xor(l, off, 64);
    if (ln == 0) sl[w] = l;
    __syncthreads();
    l = sl[0] + sl[1] + sl[2] + sl[3];
    float inv = 1.0f / l;
    attn[b * SS + t] = e0 * inv;
    attn[b * SS + 256 + t] = e1 * inv;
    attn[b * SS + 512 + t] = e2 * inv;
    attn[b * SS + 768 + t] = e3 * inv;
}

// ---------------------------------------------------------------------------
// k_context: ctx[b,h] += sum_s attn[b,s]*enc[b,s,h]  (1024 blocks: b x 16 s-chunks)
// ---------------------------------------------------------------------------
__global__ __launch_bounds__(512)
void k_context(const float* __restrict__ enc, const float* __restrict__ attn,
               float* __restrict__ ctx) {
    int b = blockIdx.x >> 4, chunk = blockIdx.x & 15;
    int s0 = chunk * 64, t = threadIdx.x;
    __shared__ float aw[64];
    if (t < 64) aw[t] = attn[b * SS + s0 + t];
    __syncthreads();
    const float* ebase = enc + ((size_t)(b * SS + s0)) * HH + t;
    float a0 = 0, a1 = 0, a2 = 0, a3 = 0;
#pragma unroll 4
    for (int s = 0; s < 64; s += 4) {
        a0 += aw[s] * ebase[(size_t)s * HH];
        a1 += aw[s + 1] * ebase[(size_t)(s + 1) * HH];
        a2 += aw[s + 2] * ebase[(size_t)(s + 2) * HH];
        a3 += aw[s + 3] * ebase[(size_t)(s + 3) * HH];
    }
    atomicAdd(&ctx[b * HH + t], a0 + a1 + a2 + a3);
}

// ---------------------------------------------------------------------------
// k_build: lstm_in_bf16 = [emb | ctx], h_bf16, gates init = b_ih + b_hh
// ---------------------------------------------------------------------------
__global__ __launch_bounds__(256)
void k_build(const int* __restrict__ tok, const float* __restrict__ embt,
             const float* __restrict__ ctx, const float* __restrict__ hidden,
             const float* __restrict__ bih, const float* __restrict__ bhh,
             unsigned short* __restrict__ li16, unsigned short* __restrict__ h16v,
             float* __restrict__ gates) {
    int b = blockIdx.x, t = threadIdx.x;
    const float* er = embt + (size_t)tok[b] * EE;
    for (int i = t; i < HH; i += 256) {
        li16[b * 1024 + i] = f2bf(er[i]);
        li16[b * 1024 + 512 + i] = f2bf(ctx[b * HH + i]);
        h16v[b * HH + i] = f2bf(hidden[b * HH + i]);
    }
    for (int j = t; j < 2048; j += 256) gates[b * 2048 + j] = bih[j] + bhh[j];
}

// ---------------------------------------------------------------------------
// k_gates: gates += lstm_in @ W_ih^T + h @ W_hh^T  (MFMA, K split over blocks)
// grid 128 = 16 n-tiles(128) x 8 k-slices(192)
// ---------------------------------------------------------------------------
__global__ __launch_bounds__(256)
void k_gates(const unsigned short* __restrict__ li16, const unsigned short* __restrict__ h16v,
             const float* __restrict__ Wih, const float* __restrict__ Whh,
             float* __restrict__ gates) {
    int nt = blockIdx.x >> 3, ksl = blockIdx.x & 7;
    int wave = threadIdx.x >> 6, lane = threadIdx.x & 63;
    int l15 = lane & 15, lq = lane >> 4, k0 = lq * 8;
    int n0w = nt * 128 + wave * 32;
    f32x4 acc[4][2];
#pragma unroll
    for (int mf = 0; mf < 4; ++mf)
#pragma unroll
        for (int nf = 0; nf < 2; ++nf) acc[mf][nf] = (f32x4){0.f, 0.f, 0.f, 0.f};

    for (int ks = 0; ks < 6; ++ks) {
        int kg = ksl * 192 + ks * 32;
        us8_t af[4];
        if (kg < 1024) {
#pragma unroll
            for (int mf = 0; mf < 4; ++mf)
                af[mf] = *(const us8_t*)(li16 + (mf * 16 + l15) * 1024 + kg + k0);
        } else {
#pragma unroll
            for (int mf = 0; mf < 4; ++mf)
                af[mf] = *(const us8_t*)(h16v + (mf * 16 + l15) * 512 + (kg - 1024) + k0);
        }
#pragma unroll
        for (int nf = 0; nf < 2; ++nf) {
            int n = n0w + nf * 16 + l15;
            us8_t bu;
            if (kg < 1024) {
                const float* wr = Wih + (size_t)n * 1024 + kg + k0;
                bu = pack8(*(const float4*)wr, *(const float4*)(wr + 4));
            } else {
                const float* wr = Whh + (size_t)n * 512 + (kg - 1024) + k0;
                bu = pack8(*(const float4*)wr, *(const float4*)(wr + 4));
            }
#pragma unroll
            for (int mf = 0; mf < 4; ++mf)
                acc[mf][nf] = __builtin_amdgcn_mfma_f32_16x16x32_bf16(
                    __builtin_bit_cast(bf16x8, af[mf]),
                    __builtin_bit_cast(bf16x8, bu), acc[mf][nf], 0, 0, 0);
        }
    }
#pragma unroll
    for (int mf = 0; mf < 4; ++mf)
#pragma unroll
        for (int nf = 0; nf < 2; ++nf)
#pragma unroll
            for (int r = 0; r < 4; ++r) {
                int row = mf * 16 + lq * 4 + r;
                int n = n0w + nf * 16 + l15;
                atomicAdd(&gates[row * 2048 + n], acc[mf][nf][r]);
            }
}

// ---------------------------------------------------------------------------
// k_lstm: pointwise LSTM cell update; writes h1/c1 (f32 out) + h1 bf16
// ---------------------------------------------------------------------------
__global__ __launch_bounds__(512)
void k_lstm(const float* __restrict__ gates, const float* __restrict__ cell,
            float* __restrict__ oh, float* __restrict__ oc,
            unsigned short* __restrict__ h116) {
    int b = blockIdx.x, t = threadIdx.x;
    float gi = gates[b * 2048 + t];
    float gf = gates[b * 2048 + 512 + t];
    float gg = gates[b * 2048 + 1024 + t];
    float go = gates[b * 2048 + 1536 + t];
    float c0 = cell[b * HH + t];
    float c1 = sigmf(gf) * c0 + sigmf(gi) * fast_tanh(gg);
    float h1 = sigmf(go) * fast_tanh(c1);
    oh[b * HH + t] = h1;
    oc[b * HH + t] = c1;
    h116[b * HH + t] = f2bf(h1);
}

// ---------------------------------------------------------------------------
// k_pred: pred = h1 @ W_out^T + b_out  (M=64, N=32000, K=512), 250 blocks x 8 waves
// ---------------------------------------------------------------------------
__global__ __launch_bounds__(512)
void k_pred(const unsigned short* __restrict__ h116, const float* __restrict__ Wout,
            const float* __restrict__ bout, float* __restrict__ pred) {
    int wave = threadIdx.x >> 6, lane = threadIdx.x & 63;
    int l15 = lane & 15, lq = lane >> 4, k0 = lq * 8;
    int n = blockIdx.x * 128 + wave * 16 + l15;
    f32x4 acc[4];
#pragma unroll
    for (int mf = 0; mf < 4; ++mf) acc[mf] = (f32x4){0.f, 0.f, 0.f, 0.f};
    const float* wr = Wout + (size_t)n * HH;
#pragma unroll 4
    for (int ks = 0; ks < 16; ++ks) {
        float4 x = *(const float4*)(wr + ks * 32 + k0);
        float4 y = *(const float4*)(wr + ks * 32 + k0 + 4);
        us8_t bu = pack8(x, y);
#pragma unroll
        for (int mf = 0; mf < 4; ++mf) {
            us8_t au = *(const us8_t*)(h116 + (mf * 16 + l15) * 512 + ks * 32 + k0);
            acc[mf] = __builtin_amdgcn_mfma_f32_16x16x32_bf16(
                __builtin_bit_cast(bf16x8, au),
                __builtin_bit_cast(bf16x8, bu), acc[mf], 0, 0, 0);
        }
    }
    float bo = bout[n];
#pragma unroll
    for (int mf = 0; mf < 4; ++mf)
#pragma unroll
        for (int r = 0; r < 4; ++r) {
            int row = mf * 16 + lq * 4 + r;
            pred[(size_t)row * VV + n] = acc[mf][r] + bo;
        }
}

// ---------------------------------------------------------------------------
extern "C" void kernel_launch(void* const* d_in, const int* in_sizes, int n_in,
                              void* d_out, int out_size, void* d_ws, size_t ws_size,
                              hipStream_t stream) {
    const int* tok = (const int*)d_in[0];
    const float* hidden = (const float*)d_in[1];
    const float* cell = (const float*)d_in[2];
    const float* enc = (const float*)d_in[3];
    const float* pos = (const float*)d_in[4];
    const unsigned char* mask = (const unsigned char*)d_in[5];
    const float* embt = (const float*)d_in[6];
    const float* Ws = (const float*)d_in[7];
    const float* Wh = (const float*)d_in[8];
    const float* Vw = (const float*)d_in[9];
    const float* Wp = (const float*)d_in[10];
    const float* bp = (const float*)d_in[11];
    const float* Wih = (const float*)d_in[12];
    const float* Whh = (const float*)d_in[13];
    const float* bih = (const float*)d_in[14];
    const float* bhh = (const float*)d_in[15];
    const float* Wout = (const float*)d_in[16];
    const float* bout = (const float*)d_in[17];

    float* out = (float*)d_out;
    float* pred = out;                  // 64*32000
    float* out_h = out + 2048000;       // 64*512
    float* out_c = out + 2080768;       // 64*512
    float* attn = out + 2113536;        // 64*1024

    char* wsb = (char*)d_ws;
    unsigned short* wh16 = (unsigned short*)(wsb);             // 512KB
    float* qs = (float*)(wsb + (512 << 10));                   // 128KB
    float* gate = (float*)(wsb + (640 << 10));                 // 256KB
    float* scores = (float*)(wsb + (896 << 10));               // 256KB
    float* ctx = (float*)(wsb + (1152 << 10));                 // 128KB
    unsigned short* li16 = (unsigned short*)(wsb + (1280 << 10));  // 128KB
    unsigned short* h16v = (unsigned short*)(wsb + (1408 << 10)); // 64KB
    float* gates = (float*)(wsb + (1472 << 10));               // 512KB
    unsigned short* h116 = (unsigned short*)(wsb + (1984 << 10)); // 64KB

    hipLaunchKernelGGL(k_prep, dim3(360), dim3(256), 0, stream,
                       hidden, Ws, Wh, pos, Wp, bp, wh16, qs, gate, ctx);
    hipLaunchKernelGGL(k_scores, dim3(512), dim3(512), 0, stream,
                       enc, wh16, qs, Vw, gate, mask, scores);
    hipLaunchKernelGGL(k_softmax, dim3(64), dim3(256), 0, stream, scores, attn);
    hipLaunchKernelGGL(k_context, dim3(1024), dim3(512), 0, stream, enc, attn, ctx);
    hipLaunchKernelGGL(k_build, dim3(64), dim3(256), 0, stream,
                       tok, embt, ctx, hidden, bih, bhh, li16, h16v, gates);
    hipLaunchKernelGGL(k_gates, dim3(128), dim3(256), 0, stream, li16, h16v, Wih, Whh, gates);
    hipLaunchKernelGGL(k_lstm, dim3(64), dim3(512), 0, stream, gates, cell, out_h, out_c, h116);
    hipLaunchKernelGGL(k_pred, dim3(250), dim3(512), 0, stream, h116, Wout, bout, pred);
}

// Round 3
// 195.298 us; speedup vs baseline: 1.2358x; 1.2358x over previous
//
#include <hip/hip_runtime.h>

#define BB 64
#define SS 1024
#define HH 512
#define EE 512
#define VV 32000
#define PP 40

typedef __attribute__((ext_vector_type(8))) __bf16 bf16x8;
typedef __attribute__((ext_vector_type(4))) float f32x4;
typedef __attribute__((ext_vector_type(8))) unsigned short us8_t;
typedef __attribute__((ext_vector_type(4))) unsigned short us4_t;

__device__ inline unsigned short f2bf(float f) {
    unsigned int u = __float_as_uint(f);
    return (unsigned short)((u + 0x7fffu + ((u >> 16) & 1u)) >> 16);
}
__device__ inline float fast_tanh(float x) {
    float e = __expf(-2.0f * fabsf(x));
    float t = (1.0f - e) / (1.0f + e);
    return copysignf(t, x);
}
__device__ inline float sigmf(float x) { return 1.0f / (1.0f + __expf(-x)); }

__device__ inline us8_t pack8(float4 x, float4 y) {
    us8_t u;
    u[0] = f2bf(x.x); u[1] = f2bf(x.y); u[2] = f2bf(x.z); u[3] = f2bf(x.w);
    u[4] = f2bf(y.x); u[5] = f2bf(y.y); u[6] = f2bf(y.z); u[7] = f2bf(y.w);
    return u;
}

// ---------------------------------------------------------------------------
// k_prep: qs = hidden @ W_s^T (blocks 0..63), W_h f32->bf16 (64..95),
//         gate = sigmoid(pos_onehot @ W_p + b_p) (96..351), zero ctx (352..359)
// ---------------------------------------------------------------------------
__global__ __launch_bounds__(256)
void k_prep(const float* __restrict__ hidden, const float* __restrict__ Ws,
            const float* __restrict__ Wh, const float* __restrict__ pos,
            const float* __restrict__ Wp, const float* __restrict__ bp,
            unsigned short* __restrict__ wh16, float* __restrict__ qs,
            float* __restrict__ gate, float* __restrict__ ctx) {
    int blk = blockIdx.x, t = threadIdx.x;
    if (blk < 64) {
        __shared__ float hb[HH];
        int b = blk;
        for (int i = t; i < HH; i += 256) hb[i] = hidden[b * HH + i];
        __syncthreads();
        for (int n = t; n < HH; n += 256) {
            const float* wr = Ws + (size_t)n * HH;
            float acc = 0.0f;
#pragma unroll 4
            for (int k = 0; k < HH; k += 4) {
                float4 w = *(const float4*)(wr + k);
                acc += w.x * hb[k] + w.y * hb[k + 1] + w.z * hb[k + 2] + w.w * hb[k + 3];
            }
            qs[b * HH + n] = acc;
        }
    } else if (blk < 96) {
        int base = (blk - 64) * 8192 + t * 4;
#pragma unroll
        for (int j = 0; j < 8; ++j) {
            int idx = base + j * 1024;
            float4 x = *(const float4*)(Wh + idx);
            us4_t v;
            v[0] = f2bf(x.x); v[1] = f2bf(x.y); v[2] = f2bf(x.z); v[3] = f2bf(x.w);
            *(us4_t*)(wh16 + idx) = v;
        }
    } else if (blk < 352) {
        int idx = (blk - 96) * 256 + t;  // 0..65535 = b*S+s
        const float* pr = pos + (size_t)idx * PP;
        float acc = bp[0];
#pragma unroll
        for (int j = 0; j < 10; ++j) {
            float4 x = *(const float4*)(pr + j * 4);
            acc += x.x * Wp[j * 4] + x.y * Wp[j * 4 + 1] + x.z * Wp[j * 4 + 2] + x.w * Wp[j * 4 + 3];
        }
        gate[idx] = sigmf(acc);
    } else {
        int idx = (blk - 352) * 256 + t;  // 2048 threads x 16 = 32768 (ctx zero)
#pragma unroll
        for (int j = 0; j < 16; ++j) ctx[idx * 16 + j] = 0.0f;
    }
}

// ---------------------------------------------------------------------------
// k_scores v2: waves own n (W_h A-frags in regs), enc tiles stream via LDS.
// grid 1024 = nh(2 n-halves, bid>>9 so pairs share an XCD) x b(64) x sc(8 x 128 s).
// Block: 8 waves x 32 n each. LDS tile: k-major slots, conflict-free both sides:
//   phys16(slot,row) byte = slot*256 + ((row ^ (slot&15))&15)*16, slot = ks*4+lq.
// Output: part[nh][b][s] partial score sums (no atomics).
// ---------------------------------------------------------------------------
__global__ __launch_bounds__(512)
void k_scores(const float* __restrict__ enc, const unsigned short* __restrict__ wh16,
              const float* __restrict__ qs, const float* __restrict__ Vw,
              float* __restrict__ part) {
    __shared__ unsigned short tile[8192];   // 16KB
    __shared__ float pbuf[8][128];
    int bid = blockIdx.x;
    int nh = bid >> 9, rest = bid & 511;
    int b = rest >> 3, sc = rest & 7;
    int s0 = sc * 128;
    int w = threadIdx.x >> 6, lane = threadIdx.x & 63;
    int l15 = lane & 15, lq = lane >> 4;
    int n0w = nh * 256 + w * 32;

    // A-frags: W_h rows (n), 32 per wave, whole K=512 in regs (128 VGPR)
    us8_t areg[2][16];
    const unsigned short* abase = wh16 + (size_t)(n0w + l15) * 512 + lq * 8;
#pragma unroll
    for (int nf = 0; nf < 2; ++nf)
#pragma unroll
        for (int ks = 0; ks < 16; ++ks)
            areg[nf][ks] = *(const us8_t*)(abase + nf * 16 * 512 + ks * 32);

    float qv[2][4], vw[2][4];
#pragma unroll
    for (int nf = 0; nf < 2; ++nf)
#pragma unroll
        for (int r = 0; r < 4; ++r) {
            int n = n0w + nf * 16 + lq * 4 + r;
            qv[nf][r] = qs[b * HH + n];
            vw[nf][r] = Vw[n];
        }

    // staging mapping: thread -> (s-row sr, 16-elem k-chunk seg)
    int sr = threadIdx.x >> 5, seg = threadIdx.x & 31;
    const float* gsrc = enc + ((size_t)(b * SS + s0 + sr)) * HH + seg * 16;
    int slot1 = (seg >> 1) * 4 + (seg & 1) * 2;
    unsigned short* wp1 = tile + slot1 * 128 + ((sr ^ (slot1 & 15)) & 15) * 8;
    unsigned short* wp2 = tile + (slot1 + 1) * 128 + ((sr ^ ((slot1 + 1) & 15)) & 15) * 8;

    for (int st = 0; st < 8; ++st) {
        const float* g = gsrc + (size_t)st * 16 * HH;
        float4 x0 = *(const float4*)(g);
        float4 x1 = *(const float4*)(g + 4);
        float4 x2 = *(const float4*)(g + 8);
        float4 x3 = *(const float4*)(g + 12);
        us8_t v1 = pack8(x0, x1);
        us8_t v2 = pack8(x2, x3);
        __syncthreads();                 // previous compute done before overwrite
        *(us8_t*)wp1 = v1;
        *(us8_t*)wp2 = v2;
        __syncthreads();                 // tile ready

        f32x4 acc0 = {0.f, 0.f, 0.f, 0.f};
        f32x4 acc1 = {0.f, 0.f, 0.f, 0.f};
#pragma unroll
        for (int ks = 0; ks < 16; ++ks) {
            int u = ks * 4 + lq;
            us8_t bf = *(const us8_t*)(tile + u * 128 + ((l15 ^ (u & 15)) & 15) * 8);
            acc0 = __builtin_amdgcn_mfma_f32_16x16x32_bf16(
                __builtin_bit_cast(bf16x8, areg[0][ks]),
                __builtin_bit_cast(bf16x8, bf), acc0, 0, 0, 0);
            acc1 = __builtin_amdgcn_mfma_f32_16x16x32_bf16(
                __builtin_bit_cast(bf16x8, areg[1][ks]),
                __builtin_bit_cast(bf16x8, bf), acc1, 0, 0, 0);
        }
        float p = 0.0f;
#pragma unroll
        for (int r = 0; r < 4; ++r) {
            p += fast_tanh(acc0[r] + qv[0][r]) * vw[0][r];
            p += fast_tanh(acc1[r] + qv[1][r]) * vw[1][r];
        }
        p += __shfl_xor(p, 16, 64);
        p += __shfl_xor(p, 32, 64);
        if (lq == 0) pbuf[w][st * 16 + l15] = p;
    }
    __syncthreads();
    if (threadIdx.x < 128) {
        float s = 0.0f;
#pragma unroll
        for (int ww = 0; ww < 8; ++ww) s += pbuf[ww][threadIdx.x];
        part[nh * (BB * SS) + b * SS + s0 + threadIdx.x] = s;
    }
}

// ---------------------------------------------------------------------------
// k_softmax: combine n-half partials, gate, mask, row softmax -> attn (d_out)
// ---------------------------------------------------------------------------
__global__ __launch_bounds__(256)
void k_softmax(const float* __restrict__ part, const float* __restrict__ gate,
               const unsigned char* __restrict__ mask, float* __restrict__ attn) {
    int b = blockIdx.x, t = threadIdx.x;
    int w = t >> 6, ln = t & 63;
    float v[4];
#pragma unroll
    for (int j = 0; j < 4; ++j) {
        int s = j * 256 + t;
        float raw = part[b * SS + s] + part[BB * SS + b * SS + s];
        float g = gate[b * SS + s];
        v[j] = mask[b * SS + s] ? -1e30f : raw * g;
    }
    float m = fmaxf(fmaxf(v[0], v[1]), fmaxf(v[2], v[3]));
#pragma unroll
    for (int off = 1; off < 64; off <<= 1) m = fmaxf(m, __shfl_xor(m, off, 64));
    __shared__ float sm[4], sl[4];
    if (ln == 0) sm[w] = m;
    __syncthreads();
    m = fmaxf(fmaxf(sm[0], sm[1]), fmaxf(sm[2], sm[3]));
    float e0 = __expf(v[0] - m), e1 = __expf(v[1] - m), e2 = __expf(v[2] - m), e3 = __expf(v[3] - m);
    float l = e0 + e1 + e2 + e3;
#pragma unroll
    for (int off = 1; off < 64; off <<= 1) l += __shfl_xor(l, off, 64);
    if (ln == 0) sl[w] = l;
    __syncthreads();
    l = sl[0] + sl[1] + sl[2] + sl[3];
    float inv = 1.0f / l;
    attn[b * SS + t] = e0 * inv;
    attn[b * SS + 256 + t] = e1 * inv;
    attn[b * SS + 512 + t] = e2 * inv;
    attn[b * SS + 768 + t] = e3 * inv;
}

// ---------------------------------------------------------------------------
// k_context: ctx[b,h] += sum_s attn[b,s]*enc[b,s,h]  (1024 blocks: b x 16 s-chunks)
// ---------------------------------------------------------------------------
__global__ __launch_bounds__(512)
void k_context(const float* __restrict__ enc, const float* __restrict__ attn,
               float* __restrict__ ctx) {
    int b = blockIdx.x >> 4, chunk = blockIdx.x & 15;
    int s0 = chunk * 64, t = threadIdx.x;
    __shared__ float aw[64];
    if (t < 64) aw[t] = attn[b * SS + s0 + t];
    __syncthreads();
    const float* ebase = enc + ((size_t)(b * SS + s0)) * HH + t;
    float a0 = 0, a1 = 0, a2 = 0, a3 = 0;
#pragma unroll 4
    for (int s = 0; s < 64; s += 4) {
        a0 += aw[s] * ebase[(size_t)s * HH];
        a1 += aw[s + 1] * ebase[(size_t)(s + 1) * HH];
        a2 += aw[s + 2] * ebase[(size_t)(s + 2) * HH];
        a3 += aw[s + 3] * ebase[(size_t)(s + 3) * HH];
    }
    atomicAdd(&ctx[b * HH + t], a0 + a1 + a2 + a3);
}

// ---------------------------------------------------------------------------
// k_build: lstm_in_bf16 = [emb | ctx], h_bf16, gates init = b_ih + b_hh
// ---------------------------------------------------------------------------
__global__ __launch_bounds__(256)
void k_build(const int* __restrict__ tok, const float* __restrict__ embt,
             const float* __restrict__ ctx, const float* __restrict__ hidden,
             const float* __restrict__ bih, const float* __restrict__ bhh,
             unsigned short* __restrict__ li16, unsigned short* __restrict__ h16v,
             float* __restrict__ gates) {
    int b = blockIdx.x, t = threadIdx.x;
    const float* er = embt + (size_t)tok[b] * EE;
    for (int i = t; i < HH; i += 256) {
        li16[b * 1024 + i] = f2bf(er[i]);
        li16[b * 1024 + 512 + i] = f2bf(ctx[b * HH + i]);
        h16v[b * HH + i] = f2bf(hidden[b * HH + i]);
    }
    for (int j = t; j < 2048; j += 256) gates[b * 2048 + j] = bih[j] + bhh[j];
}

// ---------------------------------------------------------------------------
// k_gates: gates += lstm_in @ W_ih^T + h @ W_hh^T  (MFMA, K split over blocks)
// ---------------------------------------------------------------------------
__global__ __launch_bounds__(256)
void k_gates(const unsigned short* __restrict__ li16, const unsigned short* __restrict__ h16v,
             const float* __restrict__ Wih, const float* __restrict__ Whh,
             float* __restrict__ gates) {
    int nt = blockIdx.x >> 3, ksl = blockIdx.x & 7;
    int wave = threadIdx.x >> 6, lane = threadIdx.x & 63;
    int l15 = lane & 15, lq = lane >> 4, k0 = lq * 8;
    int n0w = nt * 128 + wave * 32;
    f32x4 acc[4][2];
#pragma unroll
    for (int mf = 0; mf < 4; ++mf)
#pragma unroll
        for (int nf = 0; nf < 2; ++nf) acc[mf][nf] = (f32x4){0.f, 0.f, 0.f, 0.f};

    for (int ks = 0; ks < 6; ++ks) {
        int kg = ksl * 192 + ks * 32;
        us8_t af[4];
        if (kg < 1024) {
#pragma unroll
            for (int mf = 0; mf < 4; ++mf)
                af[mf] = *(const us8_t*)(li16 + (mf * 16 + l15) * 1024 + kg + k0);
        } else {
#pragma unroll
            for (int mf = 0; mf < 4; ++mf)
                af[mf] = *(const us8_t*)(h16v + (mf * 16 + l15) * 512 + (kg - 1024) + k0);
        }
#pragma unroll
        for (int nf = 0; nf < 2; ++nf) {
            int n = n0w + nf * 16 + l15;
            us8_t bu;
            if (kg < 1024) {
                const float* wr = Wih + (size_t)n * 1024 + kg + k0;
                bu = pack8(*(const float4*)wr, *(const float4*)(wr + 4));
            } else {
                const float* wr = Whh + (size_t)n * 512 + (kg - 1024) + k0;
                bu = pack8(*(const float4*)wr, *(const float4*)(wr + 4));
            }
#pragma unroll
            for (int mf = 0; mf < 4; ++mf)
                acc[mf][nf] = __builtin_amdgcn_mfma_f32_16x16x32_bf16(
                    __builtin_bit_cast(bf16x8, af[mf]),
                    __builtin_bit_cast(bf16x8, bu), acc[mf][nf], 0, 0, 0);
        }
    }
#pragma unroll
    for (int mf = 0; mf < 4; ++mf)
#pragma unroll
        for (int nf = 0; nf < 2; ++nf)
#pragma unroll
            for (int r = 0; r < 4; ++r) {
                int row = mf * 16 + lq * 4 + r;
                int n = n0w + nf * 16 + l15;
                atomicAdd(&gates[row * 2048 + n], acc[mf][nf][r]);
            }
}

// ---------------------------------------------------------------------------
// k_lstm: pointwise LSTM cell update; writes h1/c1 (f32 out) + h1 bf16
// ---------------------------------------------------------------------------
__global__ __launch_bounds__(512)
void k_lstm(const float* __restrict__ gates, const float* __restrict__ cell,
            float* __restrict__ oh, float* __restrict__ oc,
            unsigned short* __restrict__ h116) {
    int b = blockIdx.x, t = threadIdx.x;
    float gi = gates[b * 2048 + t];
    float gf = gates[b * 2048 + 512 + t];
    float gg = gates[b * 2048 + 1024 + t];
    float go = gates[b * 2048 + 1536 + t];
    float c0 = cell[b * HH + t];
    float c1 = sigmf(gf) * c0 + sigmf(gi) * fast_tanh(gg);
    float h1 = sigmf(go) * fast_tanh(c1);
    oh[b * HH + t] = h1;
    oc[b * HH + t] = c1;
    h116[b * HH + t] = f2bf(h1);
}

// ---------------------------------------------------------------------------
// k_pred: pred = h1 @ W_out^T + b_out  (M=64, N=32000, K=512)
// ---------------------------------------------------------------------------
__global__ __launch_bounds__(512)
void k_pred(const unsigned short* __restrict__ h116, const float* __restrict__ Wout,
            const float* __restrict__ bout, float* __restrict__ pred) {
    int wave = threadIdx.x >> 6, lane = threadIdx.x & 63;
    int l15 = lane & 15, lq = lane >> 4, k0 = lq * 8;
    int n = blockIdx.x * 128 + wave * 16 + l15;
    f32x4 acc[4];
#pragma unroll
    for (int mf = 0; mf < 4; ++mf) acc[mf] = (f32x4){0.f, 0.f, 0.f, 0.f};
    const float* wr = Wout + (size_t)n * HH;
#pragma unroll 4
    for (int ks = 0; ks < 16; ++ks) {
        float4 x = *(const float4*)(wr + ks * 32 + k0);
        float4 y = *(const float4*)(wr + ks * 32 + k0 + 4);
        us8_t bu = pack8(x, y);
#pragma unroll
        for (int mf = 0; mf < 4; ++mf) {
            us8_t au = *(const us8_t*)(h116 + (mf * 16 + l15) * 512 + ks * 32 + k0);
            acc[mf] = __builtin_amdgcn_mfma_f32_16x16x32_bf16(
                __builtin_bit_cast(bf16x8, au),
                __builtin_bit_cast(bf16x8, bu), acc[mf], 0, 0, 0);
        }
    }
    float bo = bout[n];
#pragma unroll
    for (int mf = 0; mf < 4; ++mf)
#pragma unroll
        for (int r = 0; r < 4; ++r) {
            int row = mf * 16 + lq * 4 + r;
            pred[(size_t)row * VV + n] = acc[mf][r] + bo;
        }
}

// ---------------------------------------------------------------------------
extern "C" void kernel_launch(void* const* d_in, const int* in_sizes, int n_in,
                              void* d_out, int out_size, void* d_ws, size_t ws_size,
                              hipStream_t stream) {
    const int* tok = (const int*)d_in[0];
    const float* hidden = (const float*)d_in[1];
    const float* cell = (const float*)d_in[2];
    const float* enc = (const float*)d_in[3];
    const float* pos = (const float*)d_in[4];
    const unsigned char* mask = (const unsigned char*)d_in[5];
    const float* embt = (const float*)d_in[6];
    const float* Ws = (const float*)d_in[7];
    const float* Wh = (const float*)d_in[8];
    const float* Vw = (const float*)d_in[9];
    const float* Wp = (const float*)d_in[10];
    const float* bp = (const float*)d_in[11];
    const float* Wih = (const float*)d_in[12];
    const float* Whh = (const float*)d_in[13];
    const float* bih = (const float*)d_in[14];
    const float* bhh = (const float*)d_in[15];
    const float* Wout = (const float*)d_in[16];
    const float* bout = (const float*)d_in[17];

    float* out = (float*)d_out;
    float* pred = out;                  // 64*32000
    float* out_h = out + 2048000;       // 64*512
    float* out_c = out + 2080768;       // 64*512
    float* attn = out + 2113536;        // 64*1024

    char* wsb = (char*)d_ws;
    unsigned short* wh16 = (unsigned short*)(wsb);                 // 512KB
    float* qs = (float*)(wsb + (512 << 10));                       // 128KB
    float* gate = (float*)(wsb + (640 << 10));                     // 256KB
    float* part = (float*)(wsb + (896 << 10));                     // 512KB (2 x 64 x 1024)
    float* ctx = (float*)(wsb + (1408 << 10));                     // 128KB
    unsigned short* li16 = (unsigned short*)(wsb + (1536 << 10));  // 128KB
    unsigned short* h16v = (unsigned short*)(wsb + (1664 << 10));  // 64KB
    float* gates = (float*)(wsb + (1728 << 10));                   // 512KB
    unsigned short* h116 = (unsigned short*)(wsb + (2240 << 10));  // 64KB

    hipLaunchKernelGGL(k_prep, dim3(360), dim3(256), 0, stream,
                       hidden, Ws, Wh, pos, Wp, bp, wh16, qs, gate, ctx);
    hipLaunchKernelGGL(k_scores, dim3(1024), dim3(512), 0, stream,
                       enc, wh16, qs, Vw, part);
    hipLaunchKernelGGL(k_softmax, dim3(64), dim3(256), 0, stream, part, gate, mask, attn);
    hipLaunchKernelGGL(k_context, dim3(1024), dim3(512), 0, stream, enc, attn, ctx);
    hipLaunchKernelGGL(k_build, dim3(64), dim3(256), 0, stream,
                       tok, embt, ctx, hidden, bih, bhh, li16, h16v, gates);
    hipLaunchKernelGGL(k_gates, dim3(128), dim3(256), 0, stream, li16, h16v, Wih, Whh, gates);
    hipLaunchKernelGGL(k_lstm, dim3(64), dim3(512), 0, stream, gates, cell, out_h, out_c, h116);
    hipLaunchKernelGGL(k_pred, dim3(250), dim3(512), 0, stream, h116, Wout, bout, pred);
}

// Round 4
// 185.704 us; speedup vs baseline: 1.2997x; 1.0517x over previous
//
#include <hip/hip_runtime.h>

#define BB 64
#define SS 1024
#define HH 512
#define EE 512
#define VV 32000
#define PP 40

typedef __attribute__((ext_vector_type(8))) __bf16 bf16x8;
typedef __attribute__((ext_vector_type(4))) float f32x4;
typedef __attribute__((ext_vector_type(8))) unsigned short us8_t;
typedef __attribute__((ext_vector_type(4))) unsigned short us4_t;

__device__ inline unsigned short f2bf(float f) {
    unsigned int u = __float_as_uint(f);
    return (unsigned short)((u + 0x7fffu + ((u >> 16) & 1u)) >> 16);
}
__device__ inline float fast_tanh(float x) {
    float e = __expf(-2.0f * fabsf(x));
    float t = (1.0f - e) / (1.0f + e);
    return copysignf(t, x);
}
__device__ inline float sigmf(float x) { return 1.0f / (1.0f + __expf(-x)); }

__device__ inline us8_t pack8(float4 x, float4 y) {
    us8_t u;
    u[0] = f2bf(x.x); u[1] = f2bf(x.y); u[2] = f2bf(x.z); u[3] = f2bf(x.w);
    u[4] = f2bf(y.x); u[5] = f2bf(y.y); u[6] = f2bf(y.z); u[7] = f2bf(y.w);
    return u;
}

// ---------------------------------------------------------------------------
// k_prep: qs = hidden @ W_s^T (blocks 0..63), W_h f32->bf16 (64..95),
//         gate = sigmoid(pos_onehot @ W_p + b_p) (96..351), zero ctx (352..359)
// ---------------------------------------------------------------------------
__global__ __launch_bounds__(256)
void k_prep(const float* __restrict__ hidden, const float* __restrict__ Ws,
            const float* __restrict__ Wh, const float* __restrict__ pos,
            const float* __restrict__ Wp, const float* __restrict__ bp,
            unsigned short* __restrict__ wh16, float* __restrict__ qs,
            float* __restrict__ gate, float* __restrict__ ctx) {
    int blk = blockIdx.x, t = threadIdx.x;
    if (blk < 64) {
        __shared__ float hb[HH];
        int b = blk;
        for (int i = t; i < HH; i += 256) hb[i] = hidden[b * HH + i];
        __syncthreads();
        for (int n = t; n < HH; n += 256) {
            const float* wr = Ws + (size_t)n * HH;
            float acc = 0.0f;
#pragma unroll 4
            for (int k = 0; k < HH; k += 4) {
                float4 w = *(const float4*)(wr + k);
                acc += w.x * hb[k] + w.y * hb[k + 1] + w.z * hb[k + 2] + w.w * hb[k + 3];
            }
            qs[b * HH + n] = acc;
        }
    } else if (blk < 96) {
        int base = (blk - 64) * 8192 + t * 4;
#pragma unroll
        for (int j = 0; j < 8; ++j) {
            int idx = base + j * 1024;
            float4 x = *(const float4*)(Wh + idx);
            us4_t v;
            v[0] = f2bf(x.x); v[1] = f2bf(x.y); v[2] = f2bf(x.z); v[3] = f2bf(x.w);
            *(us4_t*)(wh16 + idx) = v;
        }
    } else if (blk < 352) {
        int idx = (blk - 96) * 256 + t;  // 0..65535 = b*S+s
        const float* pr = pos + (size_t)idx * PP;
        float acc = bp[0];
#pragma unroll
        for (int j = 0; j < 10; ++j) {
            float4 x = *(const float4*)(pr + j * 4);
            acc += x.x * Wp[j * 4] + x.y * Wp[j * 4 + 1] + x.z * Wp[j * 4 + 2] + x.w * Wp[j * 4 + 3];
        }
        gate[idx] = sigmf(acc);
    } else {
        int idx = (blk - 352) * 256 + t;  // ctx zero
#pragma unroll
        for (int j = 0; j < 16; ++j) ctx[idx * 16 + j] = 0.0f;
    }
}

// ---------------------------------------------------------------------------
// k_scores v3: waves own n (W_h A-frags register-resident via launch_bounds),
// enc tiles double-buffered through LDS with async staging (load st+2 issued
// while computing st). grid 1024 = nh(2) x b(64) x sc(8); 8 waves x 32 n.
// LDS slot layout conflict-free both sides:
//   phys16(slot,row) = slot*256B + ((row^slot)&15)*16B, slot = ks*4+lq.
// ---------------------------------------------------------------------------
__global__ __launch_bounds__(512, 2)
void k_scores(const float* __restrict__ enc, const unsigned short* __restrict__ wh16,
              const float* __restrict__ qs, const float* __restrict__ Vw,
              float* __restrict__ part) {
    __shared__ unsigned short tile[2][8192];   // 2 x 16KB
    __shared__ float pbuf[8][128];
    int bid = blockIdx.x;
    int nh = bid >> 9, rest = bid & 511;
    int b = rest >> 3, sc = rest & 7;
    int s0 = sc * 128;
    int w = threadIdx.x >> 6, lane = threadIdx.x & 63;
    int l15 = lane & 15, lq = lane >> 4;
    int n0w = nh * 256 + w * 32;

    // A-frags: W_h rows (n), 32 per wave, whole K=512 in regs (128 VGPR)
    us8_t areg[2][16];
    const unsigned short* abase = wh16 + (size_t)(n0w + l15) * 512 + lq * 8;
#pragma unroll
    for (int nf = 0; nf < 2; ++nf)
#pragma unroll
        for (int ks = 0; ks < 16; ++ks)
            areg[nf][ks] = *(const us8_t*)(abase + nf * 16 * 512 + ks * 32);

    float qv[2][4], vw[2][4];
#pragma unroll
    for (int nf = 0; nf < 2; ++nf)
#pragma unroll
        for (int r = 0; r < 4; ++r) {
            int n = n0w + nf * 16 + lq * 4 + r;
            qv[nf][r] = qs[b * HH + n];
            vw[nf][r] = Vw[n];
        }

    // staging mapping: thread -> (s-row sr, 16-elem k-chunk seg)
    int sr = threadIdx.x >> 5, seg = threadIdx.x & 31;
    const float* gsrc = enc + ((size_t)(b * SS + s0 + sr)) * HH + seg * 16;
    int slot1 = (seg >> 1) * 4 + (seg & 1) * 2;
    int off1 = slot1 * 128 + ((sr ^ (slot1 & 15)) & 15) * 8;
    int off2 = (slot1 + 1) * 128 + ((sr ^ ((slot1 + 1) & 15)) & 15) * 8;

    // prologue: stage 0 -> buf0, issue loads for stage 1
    float4 x0 = *(const float4*)(gsrc);
    float4 x1 = *(const float4*)(gsrc + 4);
    float4 x2 = *(const float4*)(gsrc + 8);
    float4 x3 = *(const float4*)(gsrc + 12);
    *(us8_t*)(tile[0] + off1) = pack8(x0, x1);
    *(us8_t*)(tile[0] + off2) = pack8(x2, x3);
    {
        const float* g = gsrc + (size_t)16 * HH;
        x0 = *(const float4*)(g);
        x1 = *(const float4*)(g + 4);
        x2 = *(const float4*)(g + 8);
        x3 = *(const float4*)(g + 12);
    }
    __syncthreads();

    for (int st = 0; st < 8; ++st) {
        const unsigned short* tb = tile[st & 1];
        f32x4 acc0 = {0.f, 0.f, 0.f, 0.f};
        f32x4 acc1 = {0.f, 0.f, 0.f, 0.f};
#pragma unroll
        for (int ks = 0; ks < 16; ++ks) {
            int u = ks * 4 + lq;
            us8_t bf = *(const us8_t*)(tb + u * 128 + ((l15 ^ (u & 15)) & 15) * 8);
            acc0 = __builtin_amdgcn_mfma_f32_16x16x32_bf16(
                __builtin_bit_cast(bf16x8, areg[0][ks]),
                __builtin_bit_cast(bf16x8, bf), acc0, 0, 0, 0);
            acc1 = __builtin_amdgcn_mfma_f32_16x16x32_bf16(
                __builtin_bit_cast(bf16x8, areg[1][ks]),
                __builtin_bit_cast(bf16x8, bf), acc1, 0, 0, 0);
        }
        float p = 0.0f;
#pragma unroll
        for (int r = 0; r < 4; ++r) {
            p += fast_tanh(acc0[r] + qv[0][r]) * vw[0][r];
            p += fast_tanh(acc1[r] + qv[1][r]) * vw[1][r];
        }
        p += __shfl_xor(p, 16, 64);
        p += __shfl_xor(p, 32, 64);
        if (lq == 0) pbuf[w][st * 16 + l15] = p;

        if (st < 7) {
            // write next tile (data loaded a stage ago), then issue st+2 loads
            unsigned short* tn = tile[(st + 1) & 1];
            *(us8_t*)(tn + off1) = pack8(x0, x1);
            *(us8_t*)(tn + off2) = pack8(x2, x3);
            if (st < 6) {
                const float* g = gsrc + (size_t)(st + 2) * 16 * HH;
                x0 = *(const float4*)(g);
                x1 = *(const float4*)(g + 4);
                x2 = *(const float4*)(g + 8);
                x3 = *(const float4*)(g + 12);
            }
        }
        __syncthreads();
    }

    if (threadIdx.x < 128) {
        float s = 0.0f;
#pragma unroll
        for (int ww = 0; ww < 8; ++ww) s += pbuf[ww][threadIdx.x];
        part[nh * (BB * SS) + b * SS + s0 + threadIdx.x] = s;
    }
}

// ---------------------------------------------------------------------------
// k_context (softmax fused): each block (b, chunk) redundantly computes the
// row softmax denominator (no max-subtract: |score| <= ~20, exp safe in f32),
// writes its attn slice, accumulates its 64-s context chunk via atomics.
// ---------------------------------------------------------------------------
__global__ __launch_bounds__(512)
void k_context(const float* __restrict__ enc, const float* __restrict__ part,
               const float* __restrict__ gate, const unsigned char* __restrict__ mask,
               float* __restrict__ attn, float* __restrict__ ctx) {
    int b = blockIdx.x >> 4, chunk = blockIdx.x & 15;
    int s0 = chunk * 64, t = threadIdx.x;
    int w = t >> 6, ln = t & 63;
    float sum = 0.0f;
#pragma unroll
    for (int j = 0; j < 2; ++j) {
        int s = j * 512 + t;
        float raw = part[b * SS + s] + part[BB * SS + b * SS + s];
        float v = mask[b * SS + s] ? -1e30f : raw * gate[b * SS + s];
        sum += __expf(v);
    }
#pragma unroll
    for (int off = 1; off < 64; off <<= 1) sum += __shfl_xor(sum, off, 64);
    __shared__ float sl[8];
    if (ln == 0) sl[w] = sum;
    __syncthreads();
    float inv = 1.0f / (sl[0] + sl[1] + sl[2] + sl[3] + sl[4] + sl[5] + sl[6] + sl[7]);

    __shared__ float aw[64];
    if (t < 64) {
        int s = s0 + t;
        float raw = part[b * SS + s] + part[BB * SS + b * SS + s];
        float v = mask[b * SS + s] ? -1e30f : raw * gate[b * SS + s];
        float a = __expf(v) * inv;
        aw[t] = a;
        attn[b * SS + s] = a;
    }
    __syncthreads();

    const float* ebase = enc + ((size_t)(b * SS + s0)) * HH + t;
    float a0 = 0, a1 = 0, a2 = 0, a3 = 0;
#pragma unroll 4
    for (int s = 0; s < 64; s += 4) {
        a0 += aw[s] * ebase[(size_t)s * HH];
        a1 += aw[s + 1] * ebase[(size_t)(s + 1) * HH];
        a2 += aw[s + 2] * ebase[(size_t)(s + 2) * HH];
        a3 += aw[s + 3] * ebase[(size_t)(s + 3) * HH];
    }
    atomicAdd(&ctx[b * HH + t], a0 + a1 + a2 + a3);
}

// ---------------------------------------------------------------------------
// k_build: lstm_in_bf16 = [emb | ctx], h_bf16
// ---------------------------------------------------------------------------
__global__ __launch_bounds__(256)
void k_build(const int* __restrict__ tok, const float* __restrict__ embt,
             const float* __restrict__ ctx, const float* __restrict__ hidden,
             unsigned short* __restrict__ li16, unsigned short* __restrict__ h16v) {
    int b = blockIdx.x, t = threadIdx.x;
    const float* er = embt + (size_t)tok[b] * EE;
    for (int i = t; i < HH; i += 256) {
        li16[b * 1024 + i] = f2bf(er[i]);
        li16[b * 1024 + 512 + i] = f2bf(ctx[b * HH + i]);
        h16v[b * HH + i] = f2bf(hidden[b * HH + i]);
    }
}

// ---------------------------------------------------------------------------
// k_gates: gpart[ksl] = lstm_in @ W_ih^T + h @ W_hh^T  (K-slice partials,
// no atomics). grid 64 = 16 n-tiles(128) x 4 k-slices(384).
// ---------------------------------------------------------------------------
__global__ __launch_bounds__(256)
void k_gates(const unsigned short* __restrict__ li16, const unsigned short* __restrict__ h16v,
             const float* __restrict__ Wih, const float* __restrict__ Whh,
             float* __restrict__ gpart) {
    int nt = blockIdx.x >> 2, ksl = blockIdx.x & 3;
    int wave = threadIdx.x >> 6, lane = threadIdx.x & 63;
    int l15 = lane & 15, lq = lane >> 4, k0 = lq * 8;
    int n0w = nt * 128 + wave * 32;
    f32x4 acc[4][2];
#pragma unroll
    for (int mf = 0; mf < 4; ++mf)
#pragma unroll
        for (int nf = 0; nf < 2; ++nf) acc[mf][nf] = (f32x4){0.f, 0.f, 0.f, 0.f};

    for (int ks = 0; ks < 12; ++ks) {
        int kg = ksl * 384 + ks * 32;
        us8_t af[4];
        if (kg < 1024) {
#pragma unroll
            for (int mf = 0; mf < 4; ++mf)
                af[mf] = *(const us8_t*)(li16 + (mf * 16 + l15) * 1024 + kg + k0);
        } else {
#pragma unroll
            for (int mf = 0; mf < 4; ++mf)
                af[mf] = *(const us8_t*)(h16v + (mf * 16 + l15) * 512 + (kg - 1024) + k0);
        }
#pragma unroll
        for (int nf = 0; nf < 2; ++nf) {
            int n = n0w + nf * 16 + l15;
            us8_t bu;
            if (kg < 1024) {
                const float* wr = Wih + (size_t)n * 1024 + kg + k0;
                bu = pack8(*(const float4*)wr, *(const float4*)(wr + 4));
            } else {
                const float* wr = Whh + (size_t)n * 512 + (kg - 1024) + k0;
                bu = pack8(*(const float4*)wr, *(const float4*)(wr + 4));
            }
#pragma unroll
            for (int mf = 0; mf < 4; ++mf)
                acc[mf][nf] = __builtin_amdgcn_mfma_f32_16x16x32_bf16(
                    __builtin_bit_cast(bf16x8, af[mf]),
                    __builtin_bit_cast(bf16x8, bu), acc[mf][nf], 0, 0, 0);
        }
    }
#pragma unroll
    for (int mf = 0; mf < 4; ++mf)
#pragma unroll
        for (int nf = 0; nf < 2; ++nf)
#pragma unroll
            for (int r = 0; r < 4; ++r) {
                int row = mf * 16 + lq * 4 + r;
                int n = n0w + nf * 16 + l15;
                gpart[ksl * (BB * 2048) + row * 2048 + n] = acc[mf][nf][r];
            }
}

// ---------------------------------------------------------------------------
// k_lstm: sum K-slice partials + biases, pointwise cell update
// ---------------------------------------------------------------------------
__global__ __launch_bounds__(512)
void k_lstm(const float* __restrict__ gpart, const float* __restrict__ bih,
            const float* __restrict__ bhh, const float* __restrict__ cell,
            float* __restrict__ oh, float* __restrict__ oc,
            unsigned short* __restrict__ h116) {
    int b = blockIdx.x, t = threadIdx.x;
    float gi = bih[t] + bhh[t];
    float gf = bih[512 + t] + bhh[512 + t];
    float gg = bih[1024 + t] + bhh[1024 + t];
    float go = bih[1536 + t] + bhh[1536 + t];
#pragma unroll
    for (int ksl = 0; ksl < 4; ++ksl) {
        const float* gp = gpart + ksl * (BB * 2048) + b * 2048;
        gi += gp[t];
        gf += gp[512 + t];
        gg += gp[1024 + t];
        go += gp[1536 + t];
    }
    float c0 = cell[b * HH + t];
    float c1 = sigmf(gf) * c0 + sigmf(gi) * fast_tanh(gg);
    float h1 = sigmf(go) * fast_tanh(c1);
    oh[b * HH + t] = h1;
    oc[b * HH + t] = c1;
    h116[b * HH + t] = f2bf(h1);
}

// ---------------------------------------------------------------------------
// k_pred: pred = h1 @ W_out^T + b_out  (M=64, N=32000, K=512)
// ---------------------------------------------------------------------------
__global__ __launch_bounds__(512)
void k_pred(const unsigned short* __restrict__ h116, const float* __restrict__ Wout,
            const float* __restrict__ bout, float* __restrict__ pred) {
    int wave = threadIdx.x >> 6, lane = threadIdx.x & 63;
    int l15 = lane & 15, lq = lane >> 4, k0 = lq * 8;
    int n = blockIdx.x * 128 + wave * 16 + l15;
    f32x4 acc[4];
#pragma unroll
    for (int mf = 0; mf < 4; ++mf) acc[mf] = (f32x4){0.f, 0.f, 0.f, 0.f};
    const float* wr = Wout + (size_t)n * HH;
#pragma unroll 4
    for (int ks = 0; ks < 16; ++ks) {
        float4 x = *(const float4*)(wr + ks * 32 + k0);
        float4 y = *(const float4*)(wr + ks * 32 + k0 + 4);
        us8_t bu = pack8(x, y);
#pragma unroll
        for (int mf = 0; mf < 4; ++mf) {
            us8_t au = *(const us8_t*)(h116 + (mf * 16 + l15) * 512 + ks * 32 + k0);
            acc[mf] = __builtin_amdgcn_mfma_f32_16x16x32_bf16(
                __builtin_bit_cast(bf16x8, au),
                __builtin_bit_cast(bf16x8, bu), acc[mf], 0, 0, 0);
        }
    }
    float bo = bout[n];
#pragma unroll
    for (int mf = 0; mf < 4; ++mf)
#pragma unroll
        for (int r = 0; r < 4; ++r) {
            int row = mf * 16 + lq * 4 + r;
            pred[(size_t)row * VV + n] = acc[mf][r] + bo;
        }
}

// ---------------------------------------------------------------------------
extern "C" void kernel_launch(void* const* d_in, const int* in_sizes, int n_in,
                              void* d_out, int out_size, void* d_ws, size_t ws_size,
                              hipStream_t stream) {
    const int* tok = (const int*)d_in[0];
    const float* hidden = (const float*)d_in[1];
    const float* cell = (const float*)d_in[2];
    const float* enc = (const float*)d_in[3];
    const float* pos = (const float*)d_in[4];
    const unsigned char* mask = (const unsigned char*)d_in[5];
    const float* embt = (const float*)d_in[6];
    const float* Ws = (const float*)d_in[7];
    const float* Wh = (const float*)d_in[8];
    const float* Vw = (const float*)d_in[9];
    const float* Wp = (const float*)d_in[10];
    const float* bp = (const float*)d_in[11];
    const float* Wih = (const float*)d_in[12];
    const float* Whh = (const float*)d_in[13];
    const float* bih = (const float*)d_in[14];
    const float* bhh = (const float*)d_in[15];
    const float* Wout = (const float*)d_in[16];
    const float* bout = (const float*)d_in[17];

    float* out = (float*)d_out;
    float* pred = out;                  // 64*32000
    float* out_h = out + 2048000;       // 64*512
    float* out_c = out + 2080768;       // 64*512
    float* attn = out + 2113536;        // 64*1024

    char* wsb = (char*)d_ws;
    unsigned short* wh16 = (unsigned short*)(wsb);                 // 512KB
    float* qs = (float*)(wsb + (512 << 10));                       // 128KB
    float* gate = (float*)(wsb + (640 << 10));                     // 256KB
    float* part = (float*)(wsb + (896 << 10));                     // 512KB
    float* ctx = (float*)(wsb + (1408 << 10));                     // 128KB
    unsigned short* li16 = (unsigned short*)(wsb + (1536 << 10));  // 128KB
    unsigned short* h16v = (unsigned short*)(wsb + (1664 << 10));  // 64KB
    float* gpart = (float*)(wsb + (1728 << 10));                   // 2MB (4 slabs)
    unsigned short* h116 = (unsigned short*)(wsb + (3776 << 10));  // 64KB

    hipLaunchKernelGGL(k_prep, dim3(360), dim3(256), 0, stream,
                       hidden, Ws, Wh, pos, Wp, bp, wh16, qs, gate, ctx);
    hipLaunchKernelGGL(k_scores, dim3(1024), dim3(512), 0, stream,
                       enc, wh16, qs, Vw, part);
    hipLaunchKernelGGL(k_context, dim3(1024), dim3(512), 0, stream,
                       enc, part, gate, mask, attn, ctx);
    hipLaunchKernelGGL(k_build, dim3(64), dim3(256), 0, stream,
                       tok, embt, ctx, hidden, li16, h16v);
    hipLaunchKernelGGL(k_gates, dim3(64), dim3(256), 0, stream, li16, h16v, Wih, Whh, gpart);
    hipLaunchKernelGGL(k_lstm, dim3(64), dim3(512), 0, stream,
                       gpart, bih, bhh, cell, out_h, out_c, h116);
    hipLaunchKernelGGL(k_pred, dim3(250), dim3(512), 0, stream, h116, Wout, bout, pred);
}